// Round 2
// baseline (65.780 us; speedup 1.0000x reference)
//
#include <hip/hip_runtime.h>
#include <math.h>

#define EMBED 64
#define TB 8           // batch elements per block
#define BATCH 16384

__global__ __launch_bounds__(256, 8) void ncf_fused(
    const int* __restrict__ user, const int* __restrict__ item,
    const int* __restrict__ p1, const int* __restrict__ p2,
    const int* __restrict__ p3, const int* __restrict__ p4, const int* __restrict__ p5,
    const float* __restrict__ Wu, const float* __restrict__ bu,
    const float* __restrict__ Wi, const float* __restrict__ bi,
    const float* __restrict__ W1, const float* __restrict__ b1,
    const float* __restrict__ W2, const float* __restrict__ b2,
    const float* __restrict__ W3, const float* __restrict__ b3,
    float* __restrict__ out)
{
    __shared__ float xs[TB][128];    // x = [pu, ei]; later reused as h2t[64][9]
    __shared__ float h1s[TB][128];

    const int t    = threadIdx.x;
    const int lane = t & 63;
    const int wv   = t >> 6;     // 0..3
    const int blk  = blockIdx.x;

    // ---------------- Phase 1: embeddings + attention ----------------
    const float bu_l = bu[lane];
    const float bi_l = bi[lane];

    #pragma unroll
    for (int e = 0; e < TB / 4; ++e) {          // 2 elements per wave
        const int b  = wv * (TB / 4) + e;
        const int gb = blk * TB + b;

        const int iu = user[gb];
        const int ii = item[gb];
        int ip[5];
        ip[0] = p1[gb]; ip[1] = p2[gb]; ip[2] = p3[gb]; ip[3] = p4[gb]; ip[4] = p5[gb];

        const float eu = fmaxf(Wu[(size_t)iu * EMBED + lane] + bu_l, 0.0f);
        const float ei = fmaxf(Wi[(size_t)ii * EMBED + lane] + bi_l, 0.0f);

        float ep[5], w[5];
        #pragma unroll
        for (int k = 0; k < 5; ++k) {
            ep[k] = fmaxf(Wi[(size_t)ip[k] * EMBED + lane] + bi_l, 0.0f);
            w[k]  = ei * ep[k];
        }

        // butterfly reduce each dot across the 64-lane wave
        #pragma unroll
        for (int k = 0; k < 5; ++k) {
            float v = w[k];
            #pragma unroll
            for (int off = 32; off >= 1; off >>= 1)
                v += __shfl_xor(v, off, 64);
            w[k] = v;
        }

        // stable softmax over 5 (replicated per lane)
        float m = w[0];
        #pragma unroll
        for (int k = 1; k < 5; ++k) m = fmaxf(m, w[k]);
        float z[5], s = 0.0f;
        #pragma unroll
        for (int k = 0; k < 5; ++k) { z[k] = expf(w[k] - m); s += z[k]; }
        const float inv_s = 1.0f / s;

        float pum = 0.0f;
        #pragma unroll
        for (int k = 0; k < 5; ++k) pum += z[k] * ep[k];
        pum *= inv_s;

        const float pu = eu + 0.2f * pum;
        xs[b][lane]      = pu;
        xs[b][64 + lane] = ei;
    }

    __syncthreads();

    // ---------------- Phase 2: layer 1  (h1 = relu(X @ W1^T + b1)) ----------------
    // wave wv owns output cols [wv*32, wv*32+32); lane&31 = col offset;
    // lane>>5 selects elems {0..3} or {4..7}. Each W1 row read once per block.
    {
        const int c  = wv * 32 + (lane & 31);
        const int e0 = (lane >> 5) * 4;

        float acc[4];
        const float bb = b1[c];
        #pragma unroll
        for (int b = 0; b < 4; ++b) acc[b] = bb;

        for (int kk = 0; kk < 128; kk += 16) {
            float4 wr[4];
            const float4* wp = reinterpret_cast<const float4*>(&W1[c * 128 + kk]);
            #pragma unroll
            for (int j = 0; j < 4; ++j) wr[j] = wp[j];

            #pragma unroll
            for (int b = 0; b < 4; ++b) {
                const float4* xp = reinterpret_cast<const float4*>(&xs[e0 + b][kk]);
                #pragma unroll
                for (int j = 0; j < 4; ++j) {
                    const float4 xv = xp[j];
                    acc[b] += xv.x * wr[j].x + xv.y * wr[j].y + xv.z * wr[j].z + xv.w * wr[j].w;
                }
            }
        }

        #pragma unroll
        for (int b = 0; b < 4; ++b)
            h1s[e0 + b][c] = fmaxf(acc[b], 0.0f);
    }

    __syncthreads();   // h1s ready; xs free for reuse

    // ---------------- Phase 3: layer 2  (h2 = relu(H1 @ W2^T + b2)) ----------------
    // wave wv owns output rows [wv*16, wv*16+16); lane&15 = row offset;
    // lane>>4 in {0..3} selects 2 elems each. W2 rows read once per block.
    // h2 stored transposed with pad: h2t[o2][b], stride 9 (reuses xs memory)
    float* h2t = &xs[0][0];
    {
        const int c2 = wv * 16 + (lane & 15);
        const int e0 = (lane >> 4) * 2;

        float acc[2];
        const float bb = b2[c2];
        acc[0] = bb; acc[1] = bb;

        for (int kk = 0; kk < 128; kk += 16) {
            float4 wr[4];
            const float4* wp = reinterpret_cast<const float4*>(&W2[c2 * 128 + kk]);
            #pragma unroll
            for (int j = 0; j < 4; ++j) wr[j] = wp[j];

            #pragma unroll
            for (int b = 0; b < 2; ++b) {
                const float4* xp = reinterpret_cast<const float4*>(&h1s[e0 + b][kk]);
                #pragma unroll
                for (int j = 0; j < 4; ++j) {
                    const float4 xv = xp[j];
                    acc[b] += xv.x * wr[j].x + xv.y * wr[j].y + xv.z * wr[j].z + xv.w * wr[j].w;
                }
            }
        }

        h2t[c2 * 9 + e0 + 0] = fmaxf(acc[0], 0.0f);
        h2t[c2 * 9 + e0 + 1] = fmaxf(acc[1], 0.0f);
    }

    __syncthreads();

    // ---------------- Phase 4: layer 3 + sigmoid ----------------
    if (t < TB) {
        float acc = b3[0];
        #pragma unroll
        for (int j = 0; j < 64; ++j)
            acc += h2t[j * 9 + t] * W3[j];
        out[blk * TB + t] = 1.0f / (1.0f + expf(-acc));
    }
}

extern "C" void kernel_launch(void* const* d_in, const int* in_sizes, int n_in,
                              void* d_out, int out_size, void* d_ws, size_t ws_size,
                              hipStream_t stream) {
    const int*   user = (const int*)  d_in[0];
    const int*   item = (const int*)  d_in[1];
    const int*   p1   = (const int*)  d_in[2];
    const int*   p2   = (const int*)  d_in[3];
    const int*   p3   = (const int*)  d_in[4];
    const int*   p4   = (const int*)  d_in[5];
    const int*   p5   = (const int*)  d_in[6];
    const float* Wu   = (const float*)d_in[7];
    const float* bu   = (const float*)d_in[8];
    const float* Wi   = (const float*)d_in[9];
    const float* bi   = (const float*)d_in[10];
    const float* W1   = (const float*)d_in[11];
    const float* b1   = (const float*)d_in[12];
    const float* W2   = (const float*)d_in[13];
    const float* b2   = (const float*)d_in[14];
    const float* W3   = (const float*)d_in[15];
    const float* b3   = (const float*)d_in[16];
    float* out = (float*)d_out;

    dim3 grid(BATCH / TB);
    dim3 block(256);
    hipLaunchKernelGGL(ncf_fused, grid, block, 0, stream,
                       user, item, p1, p2, p3, p4, p5,
                       Wu, bu, Wi, bi, W1, b1, W2, b2, W3, b3, out);
}

// Round 3
// 40.782 us; speedup vs baseline: 1.6130x; 1.6130x over previous
//
#include <hip/hip_runtime.h>
#include <math.h>

#define EMBED 64
#define TB 16          // batch elements per block
#define BATCH 16384

__global__ __launch_bounds__(256, 4) void ncf_fused(
    const int* __restrict__ user, const int* __restrict__ item,
    const int* __restrict__ p1, const int* __restrict__ p2,
    const int* __restrict__ p3, const int* __restrict__ p4, const int* __restrict__ p5,
    const float* __restrict__ Wu, const float* __restrict__ bu,
    const float* __restrict__ Wi, const float* __restrict__ bi,
    const float* __restrict__ W1, const float* __restrict__ b1,
    const float* __restrict__ W2, const float* __restrict__ b2,
    const float* __restrict__ W3, const float* __restrict__ b3,
    float* __restrict__ out)
{
    __shared__ float xs[TB][128];    // x = [pu, ei]; later reused as h2t[64][17]
    __shared__ float h1s[TB][128];

    const int t    = threadIdx.x;
    const int lane = t & 63;
    const int wv   = t >> 6;     // 0..3
    const int blk  = blockIdx.x;

    // ---------------- Phase 1: embeddings + attention ----------------
    const float bu_l = bu[lane];
    const float bi_l = bi[lane];

    #pragma unroll
    for (int e = 0; e < TB / 4; ++e) {          // 4 elements per wave
        const int b  = wv * (TB / 4) + e;
        const int gb = blk * TB + b;

        const int iu = user[gb];
        const int ii = item[gb];
        int ip[5];
        ip[0] = p1[gb]; ip[1] = p2[gb]; ip[2] = p3[gb]; ip[3] = p4[gb]; ip[4] = p5[gb];

        const float eu = fmaxf(Wu[(size_t)iu * EMBED + lane] + bu_l, 0.0f);
        const float ei = fmaxf(Wi[(size_t)ii * EMBED + lane] + bi_l, 0.0f);

        float ep[5], w[5];
        #pragma unroll
        for (int k = 0; k < 5; ++k) {
            ep[k] = fmaxf(Wi[(size_t)ip[k] * EMBED + lane] + bi_l, 0.0f);
            w[k]  = ei * ep[k];
        }

        // butterfly reduce each dot across the 64-lane wave
        #pragma unroll
        for (int k = 0; k < 5; ++k) {
            float v = w[k];
            #pragma unroll
            for (int off = 32; off >= 1; off >>= 1)
                v += __shfl_xor(v, off, 64);
            w[k] = v;
        }

        // stable softmax over 5 (replicated per lane)
        float m = w[0];
        #pragma unroll
        for (int k = 1; k < 5; ++k) m = fmaxf(m, w[k]);
        float z[5], s = 0.0f;
        #pragma unroll
        for (int k = 0; k < 5; ++k) { z[k] = expf(w[k] - m); s += z[k]; }
        const float inv_s = 1.0f / s;

        float pum = 0.0f;
        #pragma unroll
        for (int k = 0; k < 5; ++k) pum += z[k] * ep[k];
        pum *= inv_s;

        const float pu = eu + 0.2f * pum;
        xs[b][lane]      = pu;
        xs[b][64 + lane] = ei;
    }

    __syncthreads();

    // ---------------- Phase 2: layer 1  (h1 = relu(X @ W1^T + b1)) ----------------
    // One W1 row per thread: r = t&127; h = t>>7 picks batch half (8 elems).
    // Per kk-chunk: 4 float4 weight loads feed 8*4*4 = 128 FMAs (32 FMA/load).
    {
        const int r = t & 127;
        const int h = t >> 7;                  // 0..1, elements h*8 .. h*8+7

        float acc[8];
        const float bb = b1[r];
        #pragma unroll
        for (int b = 0; b < 8; ++b) acc[b] = bb;

        for (int kk = 0; kk < 128; kk += 16) {
            float4 wr[4];
            const float4* wp = reinterpret_cast<const float4*>(&W1[r * 128 + kk]);
            #pragma unroll
            for (int j = 0; j < 4; ++j) wr[j] = wp[j];

            #pragma unroll
            for (int b = 0; b < 8; ++b) {
                const float4* xp = reinterpret_cast<const float4*>(&xs[h * 8 + b][kk]);
                #pragma unroll
                for (int j = 0; j < 4; ++j) {
                    const float4 xv = xp[j];   // wave-uniform broadcast
                    acc[b] += xv.x * wr[j].x + xv.y * wr[j].y + xv.z * wr[j].z + xv.w * wr[j].w;
                }
            }
        }

        #pragma unroll
        for (int b = 0; b < 8; ++b)
            h1s[h * 8 + b][r] = fmaxf(acc[b], 0.0f);
    }

    __syncthreads();   // h1s ready; xs free for reuse

    // ---------------- Phase 3: layer 2  (h2 = relu(H1 @ W2^T + b2)) ----------------
    // One W2 row per thread: r2 = t&63; qq = t>>6 picks 4 batch elems.
    // h2 stored transposed with pad: h2t[o2][b], stride 17 (reuses xs memory)
    float* h2t = &xs[0][0];
    {
        const int r2 = t & 63;
        const int qq = t >> 6;                 // 0..3, elements qq*4 .. qq*4+3

        float acc[4];
        const float bb = b2[r2];
        #pragma unroll
        for (int b = 0; b < 4; ++b) acc[b] = bb;

        for (int kk = 0; kk < 128; kk += 16) {
            float4 wr[4];
            const float4* wp = reinterpret_cast<const float4*>(&W2[r2 * 128 + kk]);
            #pragma unroll
            for (int j = 0; j < 4; ++j) wr[j] = wp[j];

            #pragma unroll
            for (int b = 0; b < 4; ++b) {
                const float4* xp = reinterpret_cast<const float4*>(&h1s[qq * 4 + b][kk]);
                #pragma unroll
                for (int j = 0; j < 4; ++j) {
                    const float4 xv = xp[j];   // wave-uniform broadcast
                    acc[b] += xv.x * wr[j].x + xv.y * wr[j].y + xv.z * wr[j].z + xv.w * wr[j].w;
                }
            }
        }

        #pragma unroll
        for (int b = 0; b < 4; ++b)
            h2t[r2 * 17 + qq * 4 + b] = fmaxf(acc[b], 0.0f);
    }

    __syncthreads();

    // ---------------- Phase 4: layer 3 + sigmoid ----------------
    if (t < TB) {
        float acc = b3[0];
        #pragma unroll
        for (int j = 0; j < 64; ++j)
            acc += h2t[j * 17 + t] * W3[j];
        out[blk * TB + t] = 1.0f / (1.0f + expf(-acc));
    }
}

extern "C" void kernel_launch(void* const* d_in, const int* in_sizes, int n_in,
                              void* d_out, int out_size, void* d_ws, size_t ws_size,
                              hipStream_t stream) {
    const int*   user = (const int*)  d_in[0];
    const int*   item = (const int*)  d_in[1];
    const int*   p1   = (const int*)  d_in[2];
    const int*   p2   = (const int*)  d_in[3];
    const int*   p3   = (const int*)  d_in[4];
    const int*   p4   = (const int*)  d_in[5];
    const int*   p5   = (const int*)  d_in[6];
    const float* Wu   = (const float*)d_in[7];
    const float* bu   = (const float*)d_in[8];
    const float* Wi   = (const float*)d_in[9];
    const float* bi   = (const float*)d_in[10];
    const float* W1   = (const float*)d_in[11];
    const float* b1   = (const float*)d_in[12];
    const float* W2   = (const float*)d_in[13];
    const float* b2   = (const float*)d_in[14];
    const float* W3   = (const float*)d_in[15];
    const float* b3   = (const float*)d_in[16];
    float* out = (float*)d_out;

    dim3 grid(BATCH / TB);
    dim3 block(256);
    hipLaunchKernelGGL(ncf_fused, grid, block, 0, stream,
                       user, item, p1, p2, p3, p4, p5,
                       Wu, bu, Wi, bi, W1, b1, W2, b2, W3, b3, out);
}

// Round 4
// 21.570 us; speedup vs baseline: 3.0496x; 1.8907x over previous
//
#include <hip/hip_runtime.h>
#include <hip/hip_bf16.h>
#include <math.h>

#define EMBED 64
#define TB 16          // batch elements per block
#define BATCH 16384
#define LDX 136        // bf16 elements per LDS row (128 + 8 pad -> 272B stride, conflict-free b128)

typedef __attribute__((ext_vector_type(8))) short short8;  // bf16x8 MFMA A/B frag (4 VGPR)
typedef __attribute__((ext_vector_type(4))) float f32x4;   // MFMA C/D frag

// ---- tiny pre-pass: convert W1 (16384) and W2 (8192) to bf16 in workspace ----
__global__ __launch_bounds__(256) void cvt_weights(const float* __restrict__ W1,
                                                   const float* __restrict__ W2,
                                                   __hip_bfloat16* __restrict__ Wb) {
    const int i = blockIdx.x * 256 + threadIdx.x;   // 24576 threads
    if (i < 16384)      Wb[i] = __float2bfloat16(W1[i]);
    else if (i < 24576) Wb[i] = __float2bfloat16(W2[i - 16384]);
}

__global__ __launch_bounds__(256, 4) void ncf_fused(
    const int* __restrict__ user, const int* __restrict__ item,
    const int* __restrict__ p1, const int* __restrict__ p2,
    const int* __restrict__ p3, const int* __restrict__ p4, const int* __restrict__ p5,
    const float* __restrict__ Wu, const float* __restrict__ bu,
    const float* __restrict__ Wi, const float* __restrict__ bi,
    const float* __restrict__ b1v, const float* __restrict__ b2v,
    const float* __restrict__ W3, const float* __restrict__ b3,
    const __hip_bfloat16* __restrict__ W1b, const __hip_bfloat16* __restrict__ W2b,
    float* __restrict__ out)
{
    __shared__ __align__(16) __hip_bfloat16 xs [TB * LDX];  // X  = [pu, ei] bf16
    __shared__ __align__(16) __hip_bfloat16 h1s[TB * LDX];  // h1 bf16
    __shared__ __align__(16) float          h2s[TB * 68];   // h2 fp32, pad 68

    const int t    = threadIdx.x;
    const int lane = t & 63;
    const int wv   = t >> 6;       // 0..3
    const int blk  = blockIdx.x;

    const int fr = lane & 15;      // MFMA: A row / B col / C col
    const int kg = lane >> 4;      // MFMA: k-group 0..3

    // ---- prefetch layer-1 B fragments (W1b rows, L2-resident) before the gather phase ----
    const int n0 = wv * 32;        // this wave's 32 output cols of layer 1
    short8 b1f[2][4];
    #pragma unroll
    for (int tile = 0; tile < 2; ++tile)
        #pragma unroll
        for (int kc = 0; kc < 4; ++kc)
            b1f[tile][kc] = *reinterpret_cast<const short8*>(
                &W1b[(n0 + tile * 16 + fr) * 128 + kc * 32 + kg * 8]);

    // ---------------- Phase 1: embeddings + attention (fp32) ----------------
    const float bu_l = bu[lane];
    const float bi_l = bi[lane];

    #pragma unroll
    for (int e = 0; e < TB / 4; ++e) {          // 4 batch elements per wave
        const int b  = wv * (TB / 4) + e;
        const int gb = blk * TB + b;

        const int iu = user[gb];
        const int ii = item[gb];
        int ip[5];
        ip[0] = p1[gb]; ip[1] = p2[gb]; ip[2] = p3[gb]; ip[3] = p4[gb]; ip[4] = p5[gb];

        const float eu = fmaxf(Wu[(size_t)iu * EMBED + lane] + bu_l, 0.0f);
        const float ei = fmaxf(Wi[(size_t)ii * EMBED + lane] + bi_l, 0.0f);

        float ep[5], w[5];
        #pragma unroll
        for (int k = 0; k < 5; ++k) {
            ep[k] = fmaxf(Wi[(size_t)ip[k] * EMBED + lane] + bi_l, 0.0f);
            w[k]  = ei * ep[k];
        }

        #pragma unroll
        for (int k = 0; k < 5; ++k) {
            float v = w[k];
            #pragma unroll
            for (int off = 32; off >= 1; off >>= 1)
                v += __shfl_xor(v, off, 64);
            w[k] = v;
        }

        float m = w[0];
        #pragma unroll
        for (int k = 1; k < 5; ++k) m = fmaxf(m, w[k]);
        float z[5], s = 0.0f;
        #pragma unroll
        for (int k = 0; k < 5; ++k) { z[k] = expf(w[k] - m); s += z[k]; }
        const float inv_s = 1.0f / s;

        float pum = 0.0f;
        #pragma unroll
        for (int k = 0; k < 5; ++k) pum += z[k] * ep[k];
        pum *= inv_s;

        const float pu = eu + 0.2f * pum;
        xs[b * LDX + lane]      = __float2bfloat16(pu);
        xs[b * LDX + 64 + lane] = __float2bfloat16(ei);
    }

    __syncthreads();

    // ---- prefetch layer-2 B fragments (independent of layer-1 result) ----
    const int n2 = wv * 16;        // this wave's 16 output cols of layer 2
    short8 b2f[4];
    #pragma unroll
    for (int kc = 0; kc < 4; ++kc)
        b2f[kc] = *reinterpret_cast<const short8*>(
            &W2b[(n2 + fr) * 128 + kc * 32 + kg * 8]);

    // ---------------- Layer 1: h1 = relu(X @ W1^T + b1), MFMA ----------------
    {
        const float bb0 = b1v[n0 + fr];
        const float bb1 = b1v[n0 + 16 + fr];
        f32x4 c0 = {bb0, bb0, bb0, bb0};
        f32x4 c1 = {bb1, bb1, bb1, bb1};

        #pragma unroll
        for (int kc = 0; kc < 4; ++kc) {
            const short8 a = *reinterpret_cast<const short8*>(
                &xs[fr * LDX + kc * 32 + kg * 8]);
            c0 = __builtin_amdgcn_mfma_f32_16x16x32_bf16(a, b1f[0][kc], c0, 0, 0, 0);
            c1 = __builtin_amdgcn_mfma_f32_16x16x32_bf16(a, b1f[1][kc], c1, 0, 0, 0);
        }

        #pragma unroll
        for (int r = 0; r < 4; ++r) {
            const int row = kg * 4 + r;
            h1s[row * LDX + n0 + fr]      = __float2bfloat16(fmaxf(c0[r], 0.0f));
            h1s[row * LDX + n0 + 16 + fr] = __float2bfloat16(fmaxf(c1[r], 0.0f));
        }
    }

    __syncthreads();

    // ---------------- Layer 2: h2 = relu(H1 @ W2^T + b2), MFMA ----------------
    {
        const float bb2 = b2v[n2 + fr];
        f32x4 c2 = {bb2, bb2, bb2, bb2};

        #pragma unroll
        for (int kc = 0; kc < 4; ++kc) {
            const short8 a = *reinterpret_cast<const short8*>(
                &h1s[fr * LDX + kc * 32 + kg * 8]);
            c2 = __builtin_amdgcn_mfma_f32_16x16x32_bf16(a, b2f[kc], c2, 0, 0, 0);
        }

        #pragma unroll
        for (int r = 0; r < 4; ++r)
            h2s[(kg * 4 + r) * 68 + n2 + fr] = fmaxf(c2[r], 0.0f);
    }

    __syncthreads();

    // ---------------- Layer 3 + sigmoid (wave 0) ----------------
    if (wv == 0) {
        const int b = lane >> 2;       // batch element 0..15
        const int q = lane & 3;        // k-quarter
        const float4* w3p = reinterpret_cast<const float4*>(&W3[q * 16]);
        const float4* hp  = reinterpret_cast<const float4*>(&h2s[b * 68 + q * 16]);
        float acc = 0.0f;
        #pragma unroll
        for (int j = 0; j < 4; ++j) {
            const float4 w = w3p[j];
            const float4 h = hp[j];
            acc += h.x * w.x + h.y * w.y + h.z * w.z + h.w * w.w;
        }
        acc += __shfl_xor(acc, 1, 64);
        acc += __shfl_xor(acc, 2, 64);
        if (q == 0)
            out[blk * TB + b] = 1.0f / (1.0f + expf(-(acc + b3[0])));
    }
}

extern "C" void kernel_launch(void* const* d_in, const int* in_sizes, int n_in,
                              void* d_out, int out_size, void* d_ws, size_t ws_size,
                              hipStream_t stream) {
    const int*   user = (const int*)  d_in[0];
    const int*   item = (const int*)  d_in[1];
    const int*   p1   = (const int*)  d_in[2];
    const int*   p2   = (const int*)  d_in[3];
    const int*   p3   = (const int*)  d_in[4];
    const int*   p4   = (const int*)  d_in[5];
    const int*   p5   = (const int*)  d_in[6];
    const float* Wu   = (const float*)d_in[7];
    const float* bu   = (const float*)d_in[8];
    const float* Wi   = (const float*)d_in[9];
    const float* bi   = (const float*)d_in[10];
    const float* W1   = (const float*)d_in[11];
    const float* b1   = (const float*)d_in[12];
    const float* W2   = (const float*)d_in[13];
    const float* b2   = (const float*)d_in[14];
    const float* W3   = (const float*)d_in[15];
    const float* b3   = (const float*)d_in[16];
    float* out = (float*)d_out;

    __hip_bfloat16* W1b = (__hip_bfloat16*)d_ws;          // 16384 elems
    __hip_bfloat16* W2b = W1b + 16384;                    // 8192 elems

    hipLaunchKernelGGL(cvt_weights, dim3(96), dim3(256), 0, stream, W1, W2, W1b);

    hipLaunchKernelGGL(ncf_fused, dim3(BATCH / TB), dim3(256), 0, stream,
                       user, item, p1, p2, p3, p4, p5,
                       Wu, bu, Wi, bi, b1, b2, W3, b3, W1b, W2b, out);
}